// Round 4
// baseline (251.614 us; speedup 1.0000x reference)
//
#include <hip/hip_runtime.h>

// B=2, F=T=2048, HIDDEN=1024 (16 heads x 64)
// cvt_bf16_2, transpose_w, mask_pack, gemm_qkv (z-fused), attn_fused.
// attn: S^T form (softmax rows per-lane), no online max (bounded scores,
// masked probs exactly 0), Q pre-scaled by 0.125*log2e in the GEMM epilogue.
// Round 4: Q-frags live in registers (Qs LDS eliminated), K/V double-buffered
// with ONE barrier per iter (DMA for it+1 overlaps compute of it), RNE P-pack.

typedef short v8s __attribute__((ext_vector_type(8)));
typedef float v4f __attribute__((ext_vector_type(4)));
typedef unsigned short u16;
typedef unsigned int   u32;
typedef unsigned long long u64;

constexpr float QSCALE = 0.18033688011112042f;  // 0.125 * log2(e)

__device__ __forceinline__ u16 f2bf(float f) {
    u32 u = __builtin_bit_cast(u32, f);
    u += 0x7fffu + ((u >> 16) & 1u);
    return (u16)(u >> 16);
}

// RNE bf16 pair pack (unbiased -- trunc pack cost 5e-4 of absmax in round 3)
__device__ __forceinline__ u32 pack_bf16(float a, float b) {
    u32 ua = __builtin_bit_cast(u32, a);
    u32 ub = __builtin_bit_cast(u32, b);
    ua += 0x7fffu + ((ua >> 16) & 1u);
    ub += 0x7fffu + ((ub >> 16) & 1u);
    return (ua >> 16) | (ub & 0xffff0000u);
}

__device__ __forceinline__ v8s ld8(const u16* p) {
    return *reinterpret_cast<const v8s*>(p);
}

__device__ __forceinline__ void async16(const void* g, void* l) {
    __builtin_amdgcn_global_load_lds(
        (const __attribute__((address_space(1))) u32*)g,
        (__attribute__((address_space(3))) u32*)l, 16, 0, 0);
}

// ---------------- convert fp32 -> bf16, both tensors in one launch ----------------
__global__ void cvt_bf16_2(const float* __restrict__ a, const float* __restrict__ bsrc,
                           u16* __restrict__ da, u16* __restrict__ db, int n4) {
    int i = blockIdx.x * blockDim.x + threadIdx.x;
    const float4* s;
    ushort4* d;
    int j;
    if (i < n4) { s = (const float4*)a;    d = (ushort4*)da; j = i; }
    else        { s = (const float4*)bsrc; d = (ushort4*)db; j = i - n4; }
    float4 v = s[j];
    ushort4 o;
    o.x = f2bf(v.x); o.y = f2bf(v.y); o.z = f2bf(v.z); o.w = f2bf(v.w);
    d[j] = o;
}

// ---------------- W transpose: fp32 [K][N] -> bf16 [N][K] ----------------
__global__ void transpose_w(const float* __restrict__ Wq, const float* __restrict__ Wk,
                            const float* __restrict__ Wv,
                            u16* __restrict__ Wqt, u16* __restrict__ Wkt, u16* __restrict__ Wvt) {
    __shared__ float tile[32][33];
    const float* W = blockIdx.z == 0 ? Wq : (blockIdx.z == 1 ? Wk : Wv);
    u16* Wt = blockIdx.z == 0 ? Wqt : (blockIdx.z == 1 ? Wkt : Wvt);
    const int tx = threadIdx.x, ty = threadIdx.y;
    const int n0 = blockIdx.x * 32, k0 = blockIdx.y * 32;
    for (int i = 0; i < 4; i++)
        tile[ty + i * 8][tx] = W[(size_t)(k0 + ty + i * 8) * 1024 + n0 + tx];
    __syncthreads();
    for (int i = 0; i < 4; i++)
        Wt[(size_t)(n0 + ty + i * 8) * 1024 + k0 + tx] = f2bf(tile[tx][ty + i * 8]);
}

// ---------------- mask -> bit words ----------------
__global__ void mask_pack(const int* __restrict__ mask, u64* __restrict__ words, int nwords) {
    int g = blockIdx.x * blockDim.x + threadIdx.x;
    int w = g >> 6, lane = g & 63;
    if (w < nwords) {
        int v = mask[(size_t)w * 64 + lane];
        u64 bits = __ballot(v != 0);
        if (lane == 0) words[w] = bits;
    }
}

// ---------------- z-fused bf16 GEMM: C[4096][1024] = A @ W^T + bias ----------------
__global__ __launch_bounds__(256) void gemm_qkv(
    const u16* __restrict__ Xf, const u16* __restrict__ Xt,
    const u16* __restrict__ Wqt, const u16* __restrict__ Wkt, const u16* __restrict__ Wvt,
    const float* __restrict__ bq, const float* __restrict__ bk, const float* __restrict__ bv,
    u16* __restrict__ Qb, u16* __restrict__ Kb, u16* __restrict__ Vtb) {
    const int z = blockIdx.z;
    const u16* A      = z == 0 ? Xf : Xt;
    const u16* Bt     = z == 0 ? Wqt : (z == 1 ? Wkt : Wvt);
    const float* bias = z == 0 ? bq : (z == 1 ? bk : bv);
    u16* C            = z == 0 ? Qb : (z == 1 ? Kb : Vtb);
    const int mode    = (z == 2);
    const float sc    = (z == 0) ? QSCALE : 1.0f;

    __shared__ u16 As[128 * 32];
    __shared__ u16 Bs[128 * 32];
    const uint4* Ag = reinterpret_cast<const uint4*>(A);
    const uint4* Bg = reinterpret_cast<const uint4*>(Bt);

    const int tid = threadIdx.x;
    const int lane = tid & 63, wave = tid >> 6;
    const int quad = lane >> 4, l16 = lane & 15;
    const int wm = wave >> 1, wn = wave & 1;
    const int m0 = blockIdx.x * 128, n0 = blockIdx.y * 128;

    const int cg  = (lane & 3) ^ ((lane >> 3) & 3);
    const int sw8 = (quad ^ ((l16 >> 1) & 3)) * 8;

    const int r0 = (wave * 2 + 0) * 16 + (lane >> 2);
    const int r1 = (wave * 2 + 1) * 16 + (lane >> 2);
    const uint4* ap0 = Ag + (size_t)(m0 + r0) * 128 + cg;
    const uint4* ap1 = Ag + (size_t)(m0 + r1) * 128 + cg;
    const uint4* bp0 = Bg + (size_t)(n0 + r0) * 128 + cg;
    const uint4* bp1 = Bg + (size_t)(n0 + r1) * 128 + cg;

    v4f acc[4][4];
    for (int i = 0; i < 4; i++)
        for (int j = 0; j < 4; j++) acc[i][j] = (v4f)0.0f;

    for (int k0 = 0; k0 < 32; k0++) {
        __syncthreads();
        async16(ap0, As + (wave * 2 + 0) * 512); ap0 += 4;
        async16(ap1, As + (wave * 2 + 1) * 512); ap1 += 4;
        async16(bp0, Bs + (wave * 2 + 0) * 512); bp0 += 4;
        async16(bp1, Bs + (wave * 2 + 1) * 512); bp1 += 4;
        __syncthreads();

        v8s af[4], bf[4];
        #pragma unroll
        for (int mt = 0; mt < 4; mt++) af[mt] = ld8(&As[(wm * 64 + mt * 16 + l16) * 32 + sw8]);
        #pragma unroll
        for (int nt = 0; nt < 4; nt++) bf[nt] = ld8(&Bs[(wn * 64 + nt * 16 + l16) * 32 + sw8]);
        #pragma unroll
        for (int mt = 0; mt < 4; mt++)
            #pragma unroll
            for (int nt = 0; nt < 4; nt++)
                acc[mt][nt] = __builtin_amdgcn_mfma_f32_16x16x32_bf16(af[mt], bf[nt], acc[mt][nt], 0, 0, 0);
    }

    #pragma unroll
    for (int nt = 0; nt < 4; nt++) {
        const int col = n0 + wn * 64 + nt * 16 + l16;
        const float bvv = bias[col];
        #pragma unroll
        for (int mt = 0; mt < 4; mt++) {
            const int mbase = m0 + wm * 64 + mt * 16 + quad * 4;
            if (mode == 0) {
                for (int r = 0; r < 4; r++)
                    C[(size_t)(mbase + r) * 1024 + col] = f2bf((acc[mt][nt][r] + bvv) * sc);
            } else {
                const int b = mbase >> 11, t = mbase & 2047;
                const int head = col >> 6, h = col & 63;
                ushort4 pk;
                pk.x = f2bf(acc[mt][nt][0] + bvv);
                pk.y = f2bf(acc[mt][nt][1] + bvv);
                pk.z = f2bf(acc[mt][nt][2] + bvv);
                pk.w = f2bf(acc[mt][nt][3] + bvv);
                *reinterpret_cast<ushort4*>(&C[(size_t)((b * 16 + head) * 64 + h) * 2048 + t]) = pk;
            }
        }
    }
}

// ---------------- fused flash attention (S^T / O^T, Q in regs, K/V dbuf) ----------------
// Q,K: bf16 [B][F/T][16][64] (Q pre-scaled); Vt: bf16 [B][16][64][2048]
// grid (32 bh, 16 f); block 256 = 4 waves; wave owns 32 q-rows, f-tile 128.
__global__ __launch_bounds__(256, 2) void attn_fused(
    const u16* __restrict__ Qb, const u16* __restrict__ Kb,
    const u16* __restrict__ Vtb, const u64* __restrict__ mw,
    float* __restrict__ out) {
    __shared__ u16 Ks[2][2][64][32];   // [buf][h-half][t][32]  16 KB
    __shared__ u16 Vs[2][2][64][32];   // [buf][t-half][h][32]  16 KB
    __shared__ u32 Ps[4][32 * 36];     // per-wave P (packed bf16 pairs) 18 KB

    const int tid = threadIdx.x;
    const int lane = tid & 63, wave = tid >> 6;
    const int quad = lane >> 4, l16 = lane & 15;
    const int b = blockIdx.x >> 4, head = blockIdx.x & 15;
    const int f0 = blockIdx.y * 128;

    const uint4* Kg = reinterpret_cast<const uint4*>(Kb);
    const uint4* Vg = reinterpret_cast<const uint4*>(Vtb);
    const size_t vbase4 = (size_t)(b * 16 + head) * 64 * 256;

    const int cg  = (lane & 3) ^ ((lane >> 3) & 3);
    const int sw8 = (quad ^ ((l16 >> 1) & 3)) * 8;

    // ---- Q-fragments: registers for the whole kernel (B-operand layout) ----
    v8s qf[2][2];
    #pragma unroll
    for (int kk = 0; kk < 2; kk++)
        #pragma unroll
        for (int qh = 0; qh < 2; qh++)
            qf[kk][qh] = ld8(Qb + ((size_t)(b * 2048 + f0 + wave * 32 + qh * 16 + l16) * 16 + head) * 64
                                + kk * 32 + quad * 8);

    // K/V staging pointers (2 DMA each per wave; 16 rows per instr)
    const int kr0 = ((wave * 2 + 0) * 64 + lane) >> 2;   // alloc row in [0,128)
    const int kr1 = ((wave * 2 + 1) * 64 + lane) >> 2;
    const uint4* kp0 = Kg + ((size_t)(b * 2048 + (kr0 & 63)) * 16 + head) * 8 + (kr0 >> 6) * 4 + cg;
    const uint4* kp1 = Kg + ((size_t)(b * 2048 + (kr1 & 63)) * 16 + head) * 8 + (kr1 >> 6) * 4 + cg;
    const uint4* vp0 = Vg + vbase4 + (size_t)(kr0 & 63) * 256 + (kr0 >> 6) * 4 + cg;
    const uint4* vp1 = Vg + vbase4 + (size_t)(kr1 & 63) * 256 + (kr1 >> 6) * 4 + cg;
    const int dK0 = (wave * 2 + 0) * 512, dK1 = (wave * 2 + 1) * 512;

    float lsum[2] = {0.f, 0.f};
    v4f accO[2][4];
    #pragma unroll
    for (int qh = 0; qh < 2; qh++)
        for (int ht = 0; ht < 4; ht++) accO[qh][ht] = (v4f)0.0f;

    u32* myPs = Ps[wave];
    const u64* mrow = mw + (size_t)(b * 2048 + f0 + wave * 32 + l16) * 32;

    // prologue: stage tile 0 into buf 0
    async16(kp0, (u16*)Ks + dK0); kp0 += 8192;
    async16(kp1, (u16*)Ks + dK1); kp1 += 8192;
    async16(vp0, (u16*)Vs + dK0); vp0 += 8;
    async16(vp1, (u16*)Vs + dK1); vp1 += 8;
    __syncthreads();

    for (int it = 0; it < 32; it++) {
        const int cur = it & 1, nxt = cur ^ 1;
        if (it < 31) {   // prefetch tile it+1 into the other buffer (overlaps compute)
            async16(kp0, (u16*)Ks + nxt * 4096 + dK0); kp0 += 8192;
            async16(kp1, (u16*)Ks + nxt * 4096 + dK1); kp1 += 8192;
            async16(vp0, (u16*)Vs + nxt * 4096 + dK0); vp0 += 8;
            async16(vp1, (u16*)Vs + nxt * 4096 + dK1); vp1 += 8;
        }

        // S^T = K . Q^T : s[qh][mt], t = mt*16 + quad*4 + r, q-row = qh*16 + l16
        v4f s[2][4];
        #pragma unroll
        for (int qh = 0; qh < 2; qh++)
            for (int mt = 0; mt < 4; mt++) s[qh][mt] = (v4f)0.0f;
        #pragma unroll
        for (int kk = 0; kk < 2; kk++) {
            v8s kf[4];
            #pragma unroll
            for (int mt = 0; mt < 4; mt++) kf[mt] = ld8(&Ks[cur][kk][mt * 16 + l16][sw8]);
            #pragma unroll
            for (int qh = 0; qh < 2; qh++)
                #pragma unroll
                for (int mt = 0; mt < 4; mt++)
                    s[qh][mt] = __builtin_amdgcn_mfma_f32_16x16x32_bf16(kf[mt], qf[kk][qh], s[qh][mt], 0, 0, 0);
        }

        // p = mask ? exp2(s) : 0  (no max pass)
        u32 pk[2][8];
        #pragma unroll
        for (int qh = 0; qh < 2; qh++) {
            const u64 w = mrow[qh * 512 + it];
            const u32 lo = (u32)(w >> (quad * 4));
            const u32 hi = (u32)(w >> (quad * 4 + 32));
            float sum = 0.f;
            #pragma unroll
            for (int mt = 0; mt < 4; mt++) {
                const u32 bits = ((mt & 2) ? hi : lo) >> ((mt & 1) * 16);
                float p[4];
                #pragma unroll
                for (int r = 0; r < 4; r++) {
                    const float e = __builtin_amdgcn_exp2f(s[qh][mt][r]);
                    p[r] = ((bits >> r) & 1u) ? e : 0.0f;
                    sum += p[r];
                }
                pk[qh][mt * 2]     = pack_bf16(p[0], p[1]);
                pk[qh][mt * 2 + 1] = pack_bf16(p[2], p[3]);
            }
            lsum[qh] += sum;
        }

        // P -> per-wave LDS (wave-private: no barrier)
        #pragma unroll
        for (int qh = 0; qh < 2; qh++) {
            const int row = qh * 16 + l16;
            #pragma unroll
            for (int mt = 0; mt < 4; mt++)
                *reinterpret_cast<uint2*>(&myPs[row * 36 + mt * 8 + quad * 2]) =
                    make_uint2(pk[qh][mt * 2], pk[qh][mt * 2 + 1]);
        }

        // O^T += V . P^T
        #pragma unroll
        for (int kk = 0; kk < 2; kk++) {
            v8s vf[4];
            #pragma unroll
            for (int ht = 0; ht < 4; ht++) vf[ht] = ld8(&Vs[cur][kk][ht * 16 + l16][sw8]);
            #pragma unroll
            for (int qh = 0; qh < 2; qh++) {
                const v8s pf = *reinterpret_cast<const v8s*>(
                    &myPs[(qh * 16 + l16) * 36 + kk * 16 + quad * 4]);
                #pragma unroll
                for (int ht = 0; ht < 4; ht++)
                    accO[qh][ht] = __builtin_amdgcn_mfma_f32_16x16x32_bf16(vf[ht], pf, accO[qh][ht], 0, 0, 0);
            }
        }

        __syncthreads();   // all waves done with buf[cur]; DMA(it+1) drained (long in flight)
    }

    #pragma unroll
    for (int qh = 0; qh < 2; qh++) {
        float l = lsum[qh];
        l += __shfl_xor(l, 16);
        l += __shfl_xor(l, 32);
        const float inv = 1.0f / l;
        const size_t ro = (size_t)(b * 2048 + f0 + wave * 32 + qh * 16 + l16) * 1024 + head * 64;
        #pragma unroll
        for (int ht = 0; ht < 4; ht++) {
            float4 o;
            o.x = accO[qh][ht][0] * inv;
            o.y = accO[qh][ht][1] * inv;
            o.z = accO[qh][ht][2] * inv;
            o.w = accO[qh][ht][3] * inv;
            *reinterpret_cast<float4*>(&out[ro + ht * 16 + quad * 4]) = o;
        }
    }
}

extern "C" void kernel_launch(void* const* d_in, const int* in_sizes, int n_in,
                              void* d_out, int out_size, void* d_ws, size_t ws_size,
                              hipStream_t stream) {
    const float* from = (const float*)d_in[0];
    const float* to   = (const float*)d_in[1];
    const int*   mask = (const int*)d_in[2];
    const float* Wq = (const float*)d_in[3];
    const float* bq = (const float*)d_in[4];
    const float* Wk = (const float*)d_in[5];
    const float* bk = (const float*)d_in[6];
    const float* Wv = (const float*)d_in[7];
    const float* bv = (const float*)d_in[8];
    float* out = (float*)d_out;

    u16* Xf  = (u16*)d_ws;            // 4096x1024
    u16* Xt  = Xf  + 4194304;
    u16* Wqt = Xt  + 4194304;         // 1024x1024 each
    u16* Wkt = Wqt + 1048576;
    u16* Wvt = Wkt + 1048576;
    u16* Qb  = Wvt + 1048576;         // 4096x1024
    u16* Kb  = Qb  + 4194304;
    u16* Vtb = Kb  + 4194304;         // [2][16][64][2048]
    u64* mwords = (u64*)(Vtb + 4194304);  // 2*2048*32 words

    cvt_bf16_2<<<8192, 256, 0, stream>>>(from, to, Xf, Xt, 1048576);
    transpose_w<<<dim3(32, 32, 3), dim3(32, 8), 0, stream>>>(Wq, Wk, Wv, Wqt, Wkt, Wvt);
    mask_pack<<<32768, 256, 0, stream>>>(mask, mwords, 131072);

    gemm_qkv<<<dim3(32, 8, 3), 256, 0, stream>>>(Xf, Xt, Wqt, Wkt, Wvt, bq, bk, bv, Qb, Kb, Vtb);

    attn_fused<<<dim3(32, 16), 256, 0, stream>>>(Qb, Kb, Vtb, mwords, out);
}

// Round 5
// 238.015 us; speedup vs baseline: 1.0571x; 1.0571x over previous
//
#include <hip/hip_runtime.h>

// B=2, F=T=2048, HIDDEN=1024 (16 heads x 64)
// prep (cvt+transpose_w+mask_pack fused), gemm_qkv (z-fused), attn_fused (t-split
// partials, grid 1024 = 4 blocks/CU), reduce_out ((O0+O1)/(l0+l1)).
// attn: S^T form (softmax rows per-lane), no online max (bounded scores, masked
// probs exactly 0, partials exactly additive), Q pre-scaled by 0.125*log2e.
// l via ones-MFMA on the LDS-rounded P (numerator/denominator rounding cancels).

typedef short v8s __attribute__((ext_vector_type(8)));
typedef float v4f __attribute__((ext_vector_type(4)));
typedef unsigned short u16;
typedef unsigned int   u32;
typedef unsigned long long u64;

constexpr float QSCALE = 0.18033688011112042f;  // 0.125 * log2(e)

__device__ __forceinline__ u16 f2bf(float f) {
    u32 u = __builtin_bit_cast(u32, f);
    u += 0x7fffu + ((u >> 16) & 1u);
    return (u16)(u >> 16);
}

// truncating bf16 pair pack (absmax 9.8e-4 in round 3 -- 2.7x under threshold)
__device__ __forceinline__ u32 pack_trunc(float a, float b) {
    u32 ua = __builtin_bit_cast(u32, a);
    u32 ub = __builtin_bit_cast(u32, b);
    return (ua >> 16) | (ub & 0xffff0000u);
}

__device__ __forceinline__ v8s ld8(const u16* p) {
    return *reinterpret_cast<const v8s*>(p);
}

__device__ __forceinline__ void async16(const void* g, void* l) {
    __builtin_amdgcn_global_load_lds(
        (const __attribute__((address_space(1))) u32*)g,
        (__attribute__((address_space(3))) u32*)l, 16, 0, 0);
}

// ---------------- fused prep: cvt x2 | W transpose | mask pack ----------------
// grid: [0,8192) cvt, [8192,11264) transpose, [11264,44032) mask
__global__ __launch_bounds__(256) void prep(
    const float* __restrict__ from, const float* __restrict__ to,
    u16* __restrict__ Xf, u16* __restrict__ Xt,
    const float* __restrict__ Wq, const float* __restrict__ Wk, const float* __restrict__ Wv,
    u16* __restrict__ Wqt, u16* __restrict__ Wkt, u16* __restrict__ Wvt,
    const int* __restrict__ mask, u64* __restrict__ words) {
    __shared__ float tile[32][33];
    const int bid = blockIdx.x, tid = threadIdx.x;
    if (bid < 8192) {
        int i = bid * 256 + tid;          // over 2*1048576 float4s
        const float4* s;
        ushort4* d;
        int j;
        if (i < 1048576) { s = (const float4*)from; d = (ushort4*)Xf; j = i; }
        else             { s = (const float4*)to;   d = (ushort4*)Xt; j = i - 1048576; }
        float4 v = s[j];
        ushort4 o;
        o.x = f2bf(v.x); o.y = f2bf(v.y); o.z = f2bf(v.z); o.w = f2bf(v.w);
        d[j] = o;
    } else if (bid < 11264) {
        const int r = bid - 8192;
        const int zz = r >> 10, rem = r & 1023;
        const float* W = zz == 0 ? Wq : (zz == 1 ? Wk : Wv);
        u16* Wt = zz == 0 ? Wqt : (zz == 1 ? Wkt : Wvt);
        const int tx = tid & 31, ty = tid >> 5;
        const int n0 = (rem & 31) * 32, k0 = (rem >> 5) * 32;
        for (int i = 0; i < 4; i++)
            tile[ty + i * 8][tx] = W[(size_t)(k0 + ty + i * 8) * 1024 + n0 + tx];
        __syncthreads();
        for (int i = 0; i < 4; i++)
            Wt[(size_t)(n0 + ty + i * 8) * 1024 + k0 + tx] = f2bf(tile[tx][ty + i * 8]);
    } else {
        int g = (bid - 11264) * 256 + tid;
        int w = g >> 6, lane = g & 63;
        int v = mask[(size_t)w * 64 + lane];
        u64 bits = __ballot(v != 0);
        if (lane == 0) words[w] = bits;
    }
}

// ---------------- z-fused bf16 GEMM: C[4096][1024] = A @ W^T + bias ----------------
__global__ __launch_bounds__(256) void gemm_qkv(
    const u16* __restrict__ Xf, const u16* __restrict__ Xt,
    const u16* __restrict__ Wqt, const u16* __restrict__ Wkt, const u16* __restrict__ Wvt,
    const float* __restrict__ bq, const float* __restrict__ bk, const float* __restrict__ bv,
    u16* __restrict__ Qb, u16* __restrict__ Kb, u16* __restrict__ Vtb) {
    const int z = blockIdx.z;
    const u16* A      = z == 0 ? Xf : Xt;
    const u16* Bt     = z == 0 ? Wqt : (z == 1 ? Wkt : Wvt);
    const float* bias = z == 0 ? bq : (z == 1 ? bk : bv);
    u16* C            = z == 0 ? Qb : (z == 1 ? Kb : Vtb);
    const int mode    = (z == 2);
    const float sc    = (z == 0) ? QSCALE : 1.0f;

    __shared__ u16 As[128 * 32];
    __shared__ u16 Bs[128 * 32];
    const uint4* Ag = reinterpret_cast<const uint4*>(A);
    const uint4* Bg = reinterpret_cast<const uint4*>(Bt);

    const int tid = threadIdx.x;
    const int lane = tid & 63, wave = tid >> 6;
    const int quad = lane >> 4, l16 = lane & 15;
    const int wm = wave >> 1, wn = wave & 1;
    const int m0 = blockIdx.x * 128, n0 = blockIdx.y * 128;

    const int cg  = (lane & 3) ^ ((lane >> 3) & 3);
    const int sw8 = (quad ^ ((l16 >> 1) & 3)) * 8;

    const int r0 = (wave * 2 + 0) * 16 + (lane >> 2);
    const int r1 = (wave * 2 + 1) * 16 + (lane >> 2);
    const uint4* ap0 = Ag + (size_t)(m0 + r0) * 128 + cg;
    const uint4* ap1 = Ag + (size_t)(m0 + r1) * 128 + cg;
    const uint4* bp0 = Bg + (size_t)(n0 + r0) * 128 + cg;
    const uint4* bp1 = Bg + (size_t)(n0 + r1) * 128 + cg;

    v4f acc[4][4];
    for (int i = 0; i < 4; i++)
        for (int j = 0; j < 4; j++) acc[i][j] = (v4f)0.0f;

    for (int k0 = 0; k0 < 32; k0++) {
        __syncthreads();
        async16(ap0, As + (wave * 2 + 0) * 512); ap0 += 4;
        async16(ap1, As + (wave * 2 + 1) * 512); ap1 += 4;
        async16(bp0, Bs + (wave * 2 + 0) * 512); bp0 += 4;
        async16(bp1, Bs + (wave * 2 + 1) * 512); bp1 += 4;
        __syncthreads();

        v8s af[4], bf[4];
        #pragma unroll
        for (int mt = 0; mt < 4; mt++) af[mt] = ld8(&As[(wm * 64 + mt * 16 + l16) * 32 + sw8]);
        #pragma unroll
        for (int nt = 0; nt < 4; nt++) bf[nt] = ld8(&Bs[(wn * 64 + nt * 16 + l16) * 32 + sw8]);
        #pragma unroll
        for (int mt = 0; mt < 4; mt++)
            #pragma unroll
            for (int nt = 0; nt < 4; nt++)
                acc[mt][nt] = __builtin_amdgcn_mfma_f32_16x16x32_bf16(af[mt], bf[nt], acc[mt][nt], 0, 0, 0);
    }

    #pragma unroll
    for (int nt = 0; nt < 4; nt++) {
        const int col = n0 + wn * 64 + nt * 16 + l16;
        const float bvv = bias[col];
        #pragma unroll
        for (int mt = 0; mt < 4; mt++) {
            const int mbase = m0 + wm * 64 + mt * 16 + quad * 4;
            if (mode == 0) {
                for (int r = 0; r < 4; r++)
                    C[(size_t)(mbase + r) * 1024 + col] = f2bf((acc[mt][nt][r] + bvv) * sc);
            } else {
                const int b = mbase >> 11, t = mbase & 2047;
                const int head = col >> 6, h = col & 63;
                ushort4 pk;
                pk.x = f2bf(acc[mt][nt][0] + bvv);
                pk.y = f2bf(acc[mt][nt][1] + bvv);
                pk.z = f2bf(acc[mt][nt][2] + bvv);
                pk.w = f2bf(acc[mt][nt][3] + bvv);
                *reinterpret_cast<ushort4*>(&C[(size_t)((b * 16 + head) * 64 + h) * 2048 + t]) = pk;
            }
        }
    }
}

// ---------------- fused flash attention, t-split partials ----------------
// Q,K: bf16 [B][F/T][16][64] (Q pre-scaled); Vt: bf16 [B][16][64][2048]
// grid (32 bh, 16 f, 2 thalf); block 256 = 4 waves; wave owns 32 q-rows.
// Writes UNNORMALIZED partial O (fp32) + partial l; reduce_out combines.
__global__ __launch_bounds__(256, 4) void attn_fused(
    const u16* __restrict__ Qb, const u16* __restrict__ Kb,
    const u16* __restrict__ Vtb, const u64* __restrict__ mw,
    float* __restrict__ out, float* __restrict__ O1,
    float* __restrict__ l0w, float* __restrict__ l1w) {
    __shared__ u16 Ks[2][64][32];      // 8 KB [h-half][t][32]
    __shared__ u16 Vs[2][64][32];      // 8 KB [t-half][h][32]
    __shared__ u32 Ps[4][32 * 36];     // 18 KB per-wave P (packed bf16 pairs)

    const int tid = threadIdx.x;
    const int lane = tid & 63, wave = tid >> 6;
    const int quad = lane >> 4, l16 = lane & 15;
    const int b = blockIdx.x >> 4, head = blockIdx.x & 15;
    const int f0 = blockIdx.y * 128;
    const int thalf = blockIdx.z;
    const int tbase = thalf * 1024;

    const uint4* Kg = reinterpret_cast<const uint4*>(Kb);
    const uint4* Vg = reinterpret_cast<const uint4*>(Vtb);
    const size_t vbase4 = (size_t)(b * 16 + head) * 64 * 256;

    const int cg  = (lane & 3) ^ ((lane >> 3) & 3);
    const int sw8 = (quad ^ ((l16 >> 1) & 3)) * 8;

    // Q-fragments in registers for the whole kernel (B-operand layout)
    v8s qf[2][2];
    #pragma unroll
    for (int kk = 0; kk < 2; kk++)
        #pragma unroll
        for (int qh = 0; qh < 2; qh++)
            qf[kk][qh] = ld8(Qb + ((size_t)(b * 2048 + f0 + wave * 32 + qh * 16 + l16) * 16 + head) * 64
                                + kk * 32 + quad * 8);

    // ones A-fragment for the l-sum MFMA (bf16 1.0 = 0x3F80)
    v8s ones;
    #pragma unroll
    for (int i = 0; i < 8; i++) ones[i] = (short)0x3F80;

    // K/V staging pointers (2 DMA each per wave; 16 rows per instr)
    const int kr0 = ((wave * 2 + 0) * 64 + lane) >> 2;   // alloc row in [0,128)
    const int kr1 = ((wave * 2 + 1) * 64 + lane) >> 2;
    const uint4* kp0 = Kg + ((size_t)(b * 2048 + tbase + (kr0 & 63)) * 16 + head) * 8 + (kr0 >> 6) * 4 + cg;
    const uint4* kp1 = Kg + ((size_t)(b * 2048 + tbase + (kr1 & 63)) * 16 + head) * 8 + (kr1 >> 6) * 4 + cg;
    const uint4* vp0 = Vg + vbase4 + (size_t)(kr0 & 63) * 256 + (tbase >> 3) + (kr0 >> 6) * 4 + cg;
    const uint4* vp1 = Vg + vbase4 + (size_t)(kr1 & 63) * 256 + (tbase >> 3) + (kr1 >> 6) * 4 + cg;
    const int dK0 = (wave * 2 + 0) * 512, dK1 = (wave * 2 + 1) * 512;

    v4f accO[2][4], accL[2];
    #pragma unroll
    for (int qh = 0; qh < 2; qh++) {
        accL[qh] = (v4f)0.0f;
        for (int ht = 0; ht < 4; ht++) accO[qh][ht] = (v4f)0.0f;
    }

    u32* myPs = Ps[wave];
    const u64* mrow = mw + (size_t)(b * 2048 + f0 + wave * 32 + l16) * 32 + thalf * 16;

    for (int it = 0; it < 16; it++) {
        __syncthreads();
        async16(kp0, (u16*)Ks + dK0); kp0 += 8192;
        async16(kp1, (u16*)Ks + dK1); kp1 += 8192;
        async16(vp0, (u16*)Vs + dK0); vp0 += 8;
        async16(vp1, (u16*)Vs + dK1); vp1 += 8;
        __syncthreads();

        // S^T = K . Q^T : s[qh][mt], t = mt*16 + quad*4 + r, q-row = qh*16 + l16
        v4f s[2][4];
        #pragma unroll
        for (int qh = 0; qh < 2; qh++)
            for (int mt = 0; mt < 4; mt++) s[qh][mt] = (v4f)0.0f;
        #pragma unroll
        for (int kk = 0; kk < 2; kk++) {
            v8s kf[4];
            #pragma unroll
            for (int mt = 0; mt < 4; mt++) kf[mt] = ld8(&Ks[kk][mt * 16 + l16][sw8]);
            #pragma unroll
            for (int qh = 0; qh < 2; qh++)
                #pragma unroll
                for (int mt = 0; mt < 4; mt++)
                    s[qh][mt] = __builtin_amdgcn_mfma_f32_16x16x32_bf16(kf[mt], qf[kk][qh], s[qh][mt], 0, 0, 0);
        }

        // p = mask ? exp2(s) : 0  (no max pass; Q pre-scaled)
        u32 pk[2][8];
        #pragma unroll
        for (int qh = 0; qh < 2; qh++) {
            const u64 w = mrow[qh * 512 + it];
            const u32 lo = (u32)(w >> (quad * 4));
            const u32 hi = (u32)(w >> (quad * 4 + 32));
            #pragma unroll
            for (int mt = 0; mt < 4; mt++) {
                const u32 bits = ((mt & 2) ? hi : lo) >> ((mt & 1) * 16);
                float p[4];
                #pragma unroll
                for (int r = 0; r < 4; r++) {
                    const float e = __builtin_amdgcn_exp2f(s[qh][mt][r]);
                    p[r] = ((bits >> r) & 1u) ? e : 0.0f;
                }
                pk[qh][mt * 2]     = pack_trunc(p[0], p[1]);
                pk[qh][mt * 2 + 1] = pack_trunc(p[2], p[3]);
            }
        }

        // P -> per-wave LDS (wave-private: no barrier)
        #pragma unroll
        for (int qh = 0; qh < 2; qh++) {
            const int row = qh * 16 + l16;
            #pragma unroll
            for (int mt = 0; mt < 4; mt++)
                *reinterpret_cast<uint2*>(&myPs[row * 36 + mt * 8 + quad * 2]) =
                    make_uint2(pk[qh][mt * 2], pk[qh][mt * 2 + 1]);
        }

        // O^T += V . P^T ; l += ones . P^T  (uses the SAME rounded P as numerator)
        #pragma unroll
        for (int kk = 0; kk < 2; kk++) {
            v8s vf[4];
            #pragma unroll
            for (int ht = 0; ht < 4; ht++) vf[ht] = ld8(&Vs[kk][ht * 16 + l16][sw8]);
            #pragma unroll
            for (int qh = 0; qh < 2; qh++) {
                const v8s pf = *reinterpret_cast<const v8s*>(
                    &myPs[(qh * 16 + l16) * 36 + kk * 16 + quad * 4]);
                #pragma unroll
                for (int ht = 0; ht < 4; ht++)
                    accO[qh][ht] = __builtin_amdgcn_mfma_f32_16x16x32_bf16(vf[ht], pf, accO[qh][ht], 0, 0, 0);
                accL[qh] = __builtin_amdgcn_mfma_f32_16x16x32_bf16(ones, pf, accL[qh], 0, 0, 0);
            }
        }
    }

    float* dst = thalf ? O1 : out;
    float* lws = thalf ? l1w : l0w;
    #pragma unroll
    for (int qh = 0; qh < 2; qh++) {
        const int row = b * 2048 + f0 + wave * 32 + qh * 16 + l16;
        if (quad == 0) lws[(size_t)row * 16 + head] = accL[qh][0];
        const size_t ro = (size_t)row * 1024 + head * 64;
        #pragma unroll
        for (int ht = 0; ht < 4; ht++)
            *reinterpret_cast<float4*>(&dst[ro + ht * 16 + quad * 4]) =
                *reinterpret_cast<float4*>(&accO[qh][ht]);
    }
}

// ---------------- combine partials: out = (O0 + O1) / (l0 + l1) ----------------
__global__ __launch_bounds__(256) void reduce_out(
    float* __restrict__ out, const float* __restrict__ O1,
    const float* __restrict__ l0w, const float* __restrict__ l1w) {
    const int i4 = blockIdx.x * 256 + threadIdx.x;   // 1,048,576 float4s
    const int flat = i4 * 4;
    const int row = flat >> 10, head = (flat >> 6) & 15;
    float4 a = reinterpret_cast<float4*>(out)[i4];
    const float4 c = reinterpret_cast<const float4*>(O1)[i4];
    const float inv = 1.0f / (l0w[row * 16 + head] + l1w[row * 16 + head]);
    a.x = (a.x + c.x) * inv;
    a.y = (a.y + c.y) * inv;
    a.z = (a.z + c.z) * inv;
    a.w = (a.w + c.w) * inv;
    reinterpret_cast<float4*>(out)[i4] = a;
}

extern "C" void kernel_launch(void* const* d_in, const int* in_sizes, int n_in,
                              void* d_out, int out_size, void* d_ws, size_t ws_size,
                              hipStream_t stream) {
    const float* from = (const float*)d_in[0];
    const float* to   = (const float*)d_in[1];
    const int*   mask = (const int*)d_in[2];
    const float* Wq = (const float*)d_in[3];
    const float* bq = (const float*)d_in[4];
    const float* Wk = (const float*)d_in[5];
    const float* bk = (const float*)d_in[6];
    const float* Wv = (const float*)d_in[7];
    const float* bv = (const float*)d_in[8];
    float* out = (float*)d_out;

    u16* Xf  = (u16*)d_ws;            // 4096x1024 bf16 (dead after gemm)
    u16* Xt  = Xf  + 4194304;         // (dead after gemm)
    u16* Wqt = Xt  + 4194304;         // 1024x1024 each (dead after gemm)
    u16* Wkt = Wqt + 1048576;
    u16* Wvt = Wkt + 1048576;
    u16* Qb  = Wvt + 1048576;         // 4096x1024
    u16* Kb  = Qb  + 4194304;
    u16* Vtb = Kb  + 4194304;         // [2][16][64][2048]
    u64* mwords = (u64*)(Vtb + 4194304);  // 2*2048*32 words

    // overlays (regions dead by the time attn writes them)
    float* O1  = (float*)d_ws;        // 4.2M floats over Xf+Xt (16.8 MB)
    float* l0w = (float*)Wqt;         // 65536 floats
    float* l1w = l0w + 65536;

    prep<<<44032, 256, 0, stream>>>(from, to, Xf, Xt, Wq, Wk, Wv, Wqt, Wkt, Wvt, mask, mwords);

    gemm_qkv<<<dim3(32, 8, 3), 256, 0, stream>>>(Xf, Xt, Wqt, Wkt, Wvt, bq, bk, bv, Qb, Kb, Vtb);

    attn_fused<<<dim3(32, 16, 2), 256, 0, stream>>>(Qb, Kb, Vtb, mwords, out, O1, l0w, l1w);

    reduce_out<<<4096, 256, 0, stream>>>(out, O1, l0w, l1w);
}

// Round 6
// 226.490 us; speedup vs baseline: 1.1109x; 1.0509x over previous
//
#include <hip/hip_runtime.h>

// B=2, F=T=2048, HIDDEN=1024 (16 heads x 64)
// prep (cvt+transpose_w+mask_pack), gemm_qkv (z-fused, BK=64), attn_fused.
// attn: S^T form (softmax rows per-lane), no online max (bounded scores, masked
// probs exactly 0), Q pre-scaled by 0.125*log2e in the GEMM epilogue.
// Round 6: t-split INSIDE the block (8 waves: 0-3 t-half0, 4-7 t-half1, same
// q-rows) -> partials combined in LDS at epilogue; reduce_out + O1 traffic gone.
// GEMM BK=64 halves barrier count. XOR chunk swizzle everywhere for b128 reads.

typedef short v8s __attribute__((ext_vector_type(8)));
typedef float v4f __attribute__((ext_vector_type(4)));
typedef unsigned short u16;
typedef unsigned int   u32;
typedef unsigned long long u64;

constexpr float QSCALE = 0.18033688011112042f;  // 0.125 * log2(e)

__device__ __forceinline__ u16 f2bf(float f) {
    u32 u = __builtin_bit_cast(u32, f);
    u += 0x7fffu + ((u >> 16) & 1u);
    return (u16)(u >> 16);
}

// truncating bf16 pair pack (absmax 9.8e-4 with this in round 3 -- 2.7x margin)
__device__ __forceinline__ u32 pack_trunc(float a, float b) {
    u32 ua = __builtin_bit_cast(u32, a);
    u32 ub = __builtin_bit_cast(u32, b);
    return (ua >> 16) | (ub & 0xffff0000u);
}

__device__ __forceinline__ v8s ld8(const u16* p) {
    return *reinterpret_cast<const v8s*>(p);
}

__device__ __forceinline__ void async16(const void* g, void* l) {
    __builtin_amdgcn_global_load_lds(
        (const __attribute__((address_space(1))) u32*)g,
        (__attribute__((address_space(3))) u32*)l, 16, 0, 0);
}

// ---------------- fused prep: cvt x2 | W transpose | mask pack ----------------
__global__ __launch_bounds__(256) void prep(
    const float* __restrict__ from, const float* __restrict__ to,
    u16* __restrict__ Xf, u16* __restrict__ Xt,
    const float* __restrict__ Wq, const float* __restrict__ Wk, const float* __restrict__ Wv,
    u16* __restrict__ Wqt, u16* __restrict__ Wkt, u16* __restrict__ Wvt,
    const int* __restrict__ mask, u64* __restrict__ words) {
    __shared__ float tile[32][33];
    const int bid = blockIdx.x, tid = threadIdx.x;
    if (bid < 8192) {
        int i = bid * 256 + tid;
        const float4* s;
        ushort4* d;
        int j;
        if (i < 1048576) { s = (const float4*)from; d = (ushort4*)Xf; j = i; }
        else             { s = (const float4*)to;   d = (ushort4*)Xt; j = i - 1048576; }
        float4 v = s[j];
        ushort4 o;
        o.x = f2bf(v.x); o.y = f2bf(v.y); o.z = f2bf(v.z); o.w = f2bf(v.w);
        d[j] = o;
    } else if (bid < 11264) {
        const int r = bid - 8192;
        const int zz = r >> 10, rem = r & 1023;
        const float* W = zz == 0 ? Wq : (zz == 1 ? Wk : Wv);
        u16* Wt = zz == 0 ? Wqt : (zz == 1 ? Wkt : Wvt);
        const int tx = tid & 31, ty = tid >> 5;
        const int n0 = (rem & 31) * 32, k0 = (rem >> 5) * 32;
        for (int i = 0; i < 4; i++)
            tile[ty + i * 8][tx] = W[(size_t)(k0 + ty + i * 8) * 1024 + n0 + tx];
        __syncthreads();
        for (int i = 0; i < 4; i++)
            Wt[(size_t)(n0 + ty + i * 8) * 1024 + k0 + tx] = f2bf(tile[tx][ty + i * 8]);
    } else {
        int g = (bid - 11264) * 256 + tid;
        int w = g >> 6, lane = g & 63;
        int v = mask[(size_t)w * 64 + lane];
        u64 bits = __ballot(v != 0);
        if (lane == 0) words[w] = bits;
    }
}

// ---------------- z-fused bf16 GEMM, BK=64: C[4096][1024] = A @ W^T + bias ----------------
__global__ __launch_bounds__(256) void gemm_qkv(
    const u16* __restrict__ Xf, const u16* __restrict__ Xt,
    const u16* __restrict__ Wqt, const u16* __restrict__ Wkt, const u16* __restrict__ Wvt,
    const float* __restrict__ bq, const float* __restrict__ bk, const float* __restrict__ bv,
    u16* __restrict__ Qb, u16* __restrict__ Kb, u16* __restrict__ Vtb) {
    const int z = blockIdx.z;
    const u16* A      = z == 0 ? Xf : Xt;
    const u16* Bt     = z == 0 ? Wqt : (z == 1 ? Wkt : Wvt);
    const float* bias = z == 0 ? bq : (z == 1 ? bk : bv);
    u16* C            = z == 0 ? Qb : (z == 1 ? Kb : Vtb);
    const int mode    = (z == 2);
    const float sc    = (z == 0) ? QSCALE : 1.0f;

    __shared__ u16 As[2][128][32];   // [khalf][row][32] 16 KB
    __shared__ u16 Bs[2][128][32];
    const uint4* Ag = reinterpret_cast<const uint4*>(A);
    const uint4* Bg = reinterpret_cast<const uint4*>(Bt);

    const int tid = threadIdx.x;
    const int lane = tid & 63, wave = tid >> 6;
    const int quad = lane >> 4, l16 = lane & 15;
    const int wm = wave >> 1, wn = wave & 1;
    const int m0 = blockIdx.x * 128, n0 = blockIdx.y * 128;

    const int cg  = (lane & 3) ^ ((lane >> 3) & 3);
    const int sw8 = (quad ^ ((l16 >> 1) & 3)) * 8;

    // 4 A-instrs + 4 B-instrs per wave; instr gi covers [gi>>3][16*(gi&7)..+16][*]
    const int gi0 = wave * 4;
    const uint4 *ap0, *ap1, *ap2, *ap3, *bp0, *bp1, *bp2, *bp3;
    {
        const int rl = lane >> 2;
        const int rb0 = ((gi0 + 0) & 7) * 16 + rl, kh0 = (gi0 + 0) >> 3;
        const int rb1 = ((gi0 + 1) & 7) * 16 + rl, kh1 = (gi0 + 1) >> 3;
        const int rb2 = ((gi0 + 2) & 7) * 16 + rl, kh2 = (gi0 + 2) >> 3;
        const int rb3 = ((gi0 + 3) & 7) * 16 + rl, kh3 = (gi0 + 3) >> 3;
        ap0 = Ag + (size_t)(m0 + rb0) * 128 + kh0 * 4 + cg;
        ap1 = Ag + (size_t)(m0 + rb1) * 128 + kh1 * 4 + cg;
        ap2 = Ag + (size_t)(m0 + rb2) * 128 + kh2 * 4 + cg;
        ap3 = Ag + (size_t)(m0 + rb3) * 128 + kh3 * 4 + cg;
        bp0 = Bg + (size_t)(n0 + rb0) * 128 + kh0 * 4 + cg;
        bp1 = Bg + (size_t)(n0 + rb1) * 128 + kh1 * 4 + cg;
        bp2 = Bg + (size_t)(n0 + rb2) * 128 + kh2 * 4 + cg;
        bp3 = Bg + (size_t)(n0 + rb3) * 128 + kh3 * 4 + cg;
    }
    u16* Asl = (u16*)As + gi0 * 512;
    u16* Bsl = (u16*)Bs + gi0 * 512;

    v4f acc[4][4];
    for (int i = 0; i < 4; i++)
        for (int j = 0; j < 4; j++) acc[i][j] = (v4f)0.0f;

    for (int k0 = 0; k0 < 16; k0++) {
        __syncthreads();
        async16(ap0, Asl);        ap0 += 8;
        async16(ap1, Asl + 512);  ap1 += 8;
        async16(ap2, Asl + 1024); ap2 += 8;
        async16(ap3, Asl + 1536); ap3 += 8;
        async16(bp0, Bsl);        bp0 += 8;
        async16(bp1, Bsl + 512);  bp1 += 8;
        async16(bp2, Bsl + 1024); bp2 += 8;
        async16(bp3, Bsl + 1536); bp3 += 8;
        __syncthreads();

        #pragma unroll
        for (int kk = 0; kk < 2; kk++) {
            v8s af[4], bf[4];
            #pragma unroll
            for (int mt = 0; mt < 4; mt++) af[mt] = ld8(&As[kk][wm * 64 + mt * 16 + l16][sw8]);
            #pragma unroll
            for (int nt = 0; nt < 4; nt++) bf[nt] = ld8(&Bs[kk][wn * 64 + nt * 16 + l16][sw8]);
            #pragma unroll
            for (int mt = 0; mt < 4; mt++)
                #pragma unroll
                for (int nt = 0; nt < 4; nt++)
                    acc[mt][nt] = __builtin_amdgcn_mfma_f32_16x16x32_bf16(af[mt], bf[nt], acc[mt][nt], 0, 0, 0);
        }
    }

    #pragma unroll
    for (int nt = 0; nt < 4; nt++) {
        const int col = n0 + wn * 64 + nt * 16 + l16;
        const float bvv = bias[col];
        #pragma unroll
        for (int mt = 0; mt < 4; mt++) {
            const int mbase = m0 + wm * 64 + mt * 16 + quad * 4;
            if (mode == 0) {
                for (int r = 0; r < 4; r++)
                    C[(size_t)(mbase + r) * 1024 + col] = f2bf((acc[mt][nt][r] + bvv) * sc);
            } else {
                const int b = mbase >> 11, t = mbase & 2047;
                const int head = col >> 6, h = col & 63;
                ushort4 pk;
                pk.x = f2bf(acc[mt][nt][0] + bvv);
                pk.y = f2bf(acc[mt][nt][1] + bvv);
                pk.z = f2bf(acc[mt][nt][2] + bvv);
                pk.w = f2bf(acc[mt][nt][3] + bvv);
                *reinterpret_cast<ushort4*>(&C[(size_t)((b * 16 + head) * 64 + h) * 2048 + t]) = pk;
            }
        }
    }
}

// ---------------- fused flash attention, in-block t-split ----------------
// Q,K: bf16 [B][F/T][16][64] (Q pre-scaled); Vt: bf16 [B][16][64][2048]
// grid (32 bh, 16 f); block 512 = 8 waves. Wave w: q-rows (w&3)*32.., t-half w>>2.
// Epilogue: waves 4-7 dump partial O,l into LDS (dead Ps region); waves 0-3
// combine, normalize, store. No partial HBM traffic, no reduce kernel.
__global__ __launch_bounds__(512, 4) void attn_fused(
    const u16* __restrict__ Qb, const u16* __restrict__ Kb,
    const u16* __restrict__ Vtb, const u64* __restrict__ mw,
    float* __restrict__ out) {
    __shared__ u16 Ks[2][2][64][32];   // [thalf][khalf][t][32]  16 KB
    __shared__ u16 Vs[2][2][64][32];   // [thalf][tsub][h][32]   16 KB
    __shared__ u32 Ps[8 * 1152];       // per-wave P; reused as epilogue buffer (36 KB)

    const int tid = threadIdx.x;
    const int lane = tid & 63, wave = tid >> 6;
    const int quad = lane >> 4, l16 = lane & 15;
    const int fwave = wave & 3, tw = wave >> 2;
    const int b = blockIdx.x >> 4, head = blockIdx.x & 15;
    const int f0 = blockIdx.y * 128;

    const uint4* Kg = reinterpret_cast<const uint4*>(Kb);
    const uint4* Vg = reinterpret_cast<const uint4*>(Vtb);
    const size_t vbase4 = (size_t)(b * 16 + head) * 64 * 256;

    const int cg  = (lane & 3) ^ ((lane >> 3) & 3);
    const int sw8 = (quad ^ ((l16 >> 1) & 3)) * 8;

    // Q-fragments in registers for the whole kernel (B-operand layout)
    v8s qf[2][2];
    #pragma unroll
    for (int kk = 0; kk < 2; kk++)
        #pragma unroll
        for (int qh = 0; qh < 2; qh++)
            qf[kk][qh] = ld8(Qb + ((size_t)(b * 2048 + f0 + fwave * 32 + qh * 16 + l16) * 16 + head) * 64
                                + kk * 32 + quad * 8);

    // ones A-fragment for the l-sum MFMA (bf16 1.0 = 0x3F80)
    v8s ones;
    #pragma unroll
    for (int i = 0; i < 8; i++) ones[i] = (short)0x3F80;

    // staging: 32 instrs/iter (16 K + 16 V), 4 per wave; waves 0-3 K, 4-7 V
    const uint4 *sp0, *sp1, *sp2, *sp3;
    u16 *sd;
    size_t sinc;
    {
        const int rl = lane >> 2;
        if (wave < 4) {
            const int g0 = wave * 4;
            sd = (u16*)Ks + g0 * 512;
            sinc = 8192;
            #define KPTR(g) (Kg + ((size_t)(b * 2048 + ((g) >> 3) * 1024 + ((g) & 3) * 16 + rl) * 16 + head) * 8 \
                                + (((g) >> 2) & 1) * 4 + cg)
            sp0 = KPTR(g0); sp1 = KPTR(g0 + 1); sp2 = KPTR(g0 + 2); sp3 = KPTR(g0 + 3);
            #undef KPTR
        } else {
            const int g0 = (wave - 4) * 4;
            sd = (u16*)Vs + g0 * 512;
            sinc = 8;
            #define VPTR(g) (Vg + vbase4 + (size_t)(((g) & 3) * 16 + rl) * 256 + ((g) >> 3) * 128 \
                                + (((g) >> 2) & 1) * 4 + cg)
            sp0 = VPTR(g0); sp1 = VPTR(g0 + 1); sp2 = VPTR(g0 + 2); sp3 = VPTR(g0 + 3);
            #undef VPTR
        }
    }

    v4f accO[2][4], accL[2];
    #pragma unroll
    for (int qh = 0; qh < 2; qh++) {
        accL[qh] = (v4f)0.0f;
        for (int ht = 0; ht < 4; ht++) accO[qh][ht] = (v4f)0.0f;
    }

    u32* myPs = Ps + wave * 1152;
    const u64* mrow = mw + (size_t)(b * 2048 + f0 + fwave * 32 + l16) * 32 + tw * 16;

    for (int it = 0; it < 16; it++) {
        __syncthreads();
        async16(sp0, sd);        sp0 += sinc;
        async16(sp1, sd + 512);  sp1 += sinc;
        async16(sp2, sd + 1024); sp2 += sinc;
        async16(sp3, sd + 1536); sp3 += sinc;
        __syncthreads();

        // S^T = K . Q^T : s[qh][mt], t = mt*16 + quad*4 + r, q-row = qh*16 + l16
        v4f s[2][4];
        #pragma unroll
        for (int qh = 0; qh < 2; qh++)
            for (int mt = 0; mt < 4; mt++) s[qh][mt] = (v4f)0.0f;
        #pragma unroll
        for (int kk = 0; kk < 2; kk++) {
            v8s kf[4];
            #pragma unroll
            for (int mt = 0; mt < 4; mt++) kf[mt] = ld8(&Ks[tw][kk][mt * 16 + l16][sw8]);
            #pragma unroll
            for (int qh = 0; qh < 2; qh++)
                #pragma unroll
                for (int mt = 0; mt < 4; mt++)
                    s[qh][mt] = __builtin_amdgcn_mfma_f32_16x16x32_bf16(kf[mt], qf[kk][qh], s[qh][mt], 0, 0, 0);
        }

        // p = mask ? exp2(s) : 0  (no max pass; Q pre-scaled)
        u32 pk[2][8];
        #pragma unroll
        for (int qh = 0; qh < 2; qh++) {
            const u64 w = mrow[qh * 512 + it];
            const u32 lo = (u32)(w >> (quad * 4));
            const u32 hi = (u32)(w >> (quad * 4 + 32));
            #pragma unroll
            for (int mt = 0; mt < 4; mt++) {
                const u32 bits = ((mt & 2) ? hi : lo) >> ((mt & 1) * 16);
                float p[4];
                #pragma unroll
                for (int r = 0; r < 4; r++) {
                    const float e = __builtin_amdgcn_exp2f(s[qh][mt][r]);
                    p[r] = ((bits >> r) & 1u) ? e : 0.0f;
                }
                pk[qh][mt * 2]     = pack_trunc(p[0], p[1]);
                pk[qh][mt * 2 + 1] = pack_trunc(p[2], p[3]);
            }
        }

        // P -> per-wave LDS (wave-private: no barrier)
        #pragma unroll
        for (int qh = 0; qh < 2; qh++) {
            const int row = qh * 16 + l16;
            #pragma unroll
            for (int mt = 0; mt < 4; mt++)
                *reinterpret_cast<uint2*>(&myPs[row * 36 + mt * 8 + quad * 2]) =
                    make_uint2(pk[qh][mt * 2], pk[qh][mt * 2 + 1]);
        }

        // O^T += V . P^T ; l += ones . P^T  (same rounded P as numerator)
        #pragma unroll
        for (int kk = 0; kk < 2; kk++) {
            v8s vf[4];
            #pragma unroll
            for (int ht = 0; ht < 4; ht++) vf[ht] = ld8(&Vs[tw][kk][ht * 16 + l16][sw8]);
            #pragma unroll
            for (int qh = 0; qh < 2; qh++) {
                const v8s pf = *reinterpret_cast<const v8s*>(
                    &myPs[(qh * 16 + l16) * 36 + kk * 16 + quad * 4]);
                #pragma unroll
                for (int ht = 0; ht < 4; ht++)
                    accO[qh][ht] = __builtin_amdgcn_mfma_f32_16x16x32_bf16(vf[ht], pf, accO[qh][ht], 0, 0, 0);
                accL[qh] = __builtin_amdgcn_mfma_f32_16x16x32_bf16(ones, pf, accL[qh], 0, 0, 0);
            }
        }
    }

    // ---- epilogue: combine the two t-halves in LDS ----
    __syncthreads();                      // everyone done with Ps
    float* fb = (float*)Ps;               // 9216 floats: 4 regions x 64 lanes x 36
    if (tw == 1) {
        float* wdst = fb + fwave * 2304 + lane * 36;
        #pragma unroll
        for (int qh = 0; qh < 2; qh++)
            #pragma unroll
            for (int ht = 0; ht < 4; ht++)
                *reinterpret_cast<v4f*>(wdst + (qh * 4 + ht) * 4) = accO[qh][ht];
        wdst[32] = accL[0][0];
        wdst[33] = accL[1][0];
    }
    __syncthreads();
    if (tw == 0) {
        const float* rsrc = fb + fwave * 2304 + lane * 36;
        float inv[2];
        #pragma unroll
        for (int qh = 0; qh < 2; qh++)
            inv[qh] = 1.0f / (accL[qh][0] + rsrc[32 + qh]);
        #pragma unroll
        for (int qh = 0; qh < 2; qh++) {
            const size_t ro = (size_t)(b * 2048 + f0 + fwave * 32 + qh * 16 + l16) * 1024 + head * 64;
            #pragma unroll
            for (int ht = 0; ht < 4; ht++) {
                const v4f p = *reinterpret_cast<const v4f*>(rsrc + (qh * 4 + ht) * 4);
                float4 o;
                o.x = (accO[qh][ht][0] + p[0]) * inv[qh];
                o.y = (accO[qh][ht][1] + p[1]) * inv[qh];
                o.z = (accO[qh][ht][2] + p[2]) * inv[qh];
                o.w = (accO[qh][ht][3] + p[3]) * inv[qh];
                *reinterpret_cast<float4*>(&out[ro + ht * 16 + quad * 4]) = o;
            }
        }
    }
}

extern "C" void kernel_launch(void* const* d_in, const int* in_sizes, int n_in,
                              void* d_out, int out_size, void* d_ws, size_t ws_size,
                              hipStream_t stream) {
    const float* from = (const float*)d_in[0];
    const float* to   = (const float*)d_in[1];
    const int*   mask = (const int*)d_in[2];
    const float* Wq = (const float*)d_in[3];
    const float* bq = (const float*)d_in[4];
    const float* Wk = (const float*)d_in[5];
    const float* bk = (const float*)d_in[6];
    const float* Wv = (const float*)d_in[7];
    const float* bv = (const float*)d_in[8];
    float* out = (float*)d_out;

    u16* Xf  = (u16*)d_ws;            // 4096x1024 bf16
    u16* Xt  = Xf  + 4194304;
    u16* Wqt = Xt  + 4194304;         // 1024x1024 each
    u16* Wkt = Wqt + 1048576;
    u16* Wvt = Wkt + 1048576;
    u16* Qb  = Wvt + 1048576;         // 4096x1024
    u16* Kb  = Qb  + 4194304;
    u16* Vtb = Kb  + 4194304;         // [2][16][64][2048]
    u64* mwords = (u64*)(Vtb + 4194304);  // 2*2048*32 words

    prep<<<44032, 256, 0, stream>>>(from, to, Xf, Xt, Wq, Wk, Wv, Wqt, Wkt, Wvt, mask, mwords);

    gemm_qkv<<<dim3(32, 8, 3), 256, 0, stream>>>(Xf, Xt, Wqt, Wkt, Wvt, bq, bk, bv, Qb, Kb, Vtb);

    attn_fused<<<dim3(32, 16), 512, 0, stream>>>(Qb, Kb, Vtb, mwords, out);
}